// Round 2
// 237.479 us; speedup vs baseline: 1.0091x; 1.0091x over previous
//
#include <hip/hip_runtime.h>

#define OUT_DIM 4096
#define DPC     16
#define NCOL    65536    // OUT_DIM * DPC
#define BATCH   512
#define NWAVE   32768    // total 64-window chunks (2M windows / 64)

typedef float nvec4 __attribute__((ext_vector_type(4)));   // clang-native f32x4

// Kernel 1: bf[p] = exp((1/16 - duty[p]) * bs), double-prec exp rounded to fp32
// (bit-exact vs jnp.exp; table is 256 KiB -> L2/L3-resident for kernel 2)
__global__ void boost_table_kernel(const float* __restrict__ duty,
                                   const float* __restrict__ bs_ptr,
                                   float* __restrict__ bf) {
    int p = blockIdx.x * blockDim.x + threadIdx.x;
    if (p < NCOL) {
        float t = (0.0625f - duty[p]) * bs_ptr[0];
        bf[p] = (float)exp((double)t);
    }
}

// Kernel 2: wave-independent streaming, no __syncthreads.
// Each wave owns 64 windows (output span 1024 floats, input span 960+64 floats).
//  - winner value: out[16w+j] = x[16w+j]*(j==bj); x[output span] loaded
//    coalesced (float4) in P1, held in registers through P3. No scatter.
//  - compiler-only barriers (same-wave DS is in-order) -> out-span loads
//    stay in flight across the argmax.
//  - nontemporal out stores: out is never re-read; don't evict x from L2/L3.
__global__ __launch_bounds__(256, 8) void dkw_kernel(const float* __restrict__ x,
                                                     const float* __restrict__ bf,
                                                     float* __restrict__ out) {
    __shared__ float sb[4][1024];   // boosted span per wave, 16 KiB
    __shared__ int   sj[4][64];     // winner j per window, 1 KiB

    const int lane = threadIdx.x & 63;
    const int wv   = threadIdx.x >> 6;                 // wave in block
    const int gw   = blockIdx.x * 4 + wv;              // global wave id
    const int row  = gw >> 6;                          // 64 waves per row
    const int wc   = gw & 63;                          // chunk within row
    const int rowbase = row << 16;                     // row * 65536

    // ---- P1: stage boosted = x*bf for span [960*wc, 960*wc+1024) of row ----
    const int in_off = wc * 960;                       // 16B-aligned (/4=240*wc)
    const float4* __restrict__ xg   = (const float4*)(x + rowbase + in_off);
    const float4* __restrict__ bg   = (const float4*)(bf + in_off);
    const float4* __restrict__ xo_g = (const float4*)(x + rowbase + (wc << 10));
    float4* __restrict__ sb4 = (float4*)sb[wv];
    #pragma unroll
    for (int r = 0; r < 4; ++r) {
        const int i = lane + 64 * r;                   // 256 f4 = 1024 floats
        float4 a = xg[i];
        float4 b = bg[i];
        float4 p;
        p.x = a.x * b.x; p.y = a.y * b.y; p.z = a.z * b.z; p.w = a.w * b.w;
        sb4[i] = p;
    }
    // out-span x, coalesced; issued after staging loads (staging feeds the
    // argmax critical path), consumed only in P3 -> latency fully hidden.
    float4 xo0 = xo_g[lane];
    float4 xo1 = xo_g[lane + 64];
    float4 xo2 = xo_g[lane + 128];
    float4 xo3 = xo_g[lane + 192];
    asm volatile("" ::: "memory");   // compiler barrier; same-wave DS is in-order

    // ---- P2: lane = window wc*64+lane; argmax over LDS stride-15 ----
    {
        const float* __restrict__ p = sb[wv] + lane * 15;   // 2-way bank = free
        float best = p[0];
        int   bj   = 0;
        #pragma unroll
        for (int k = 1; k < DPC; ++k) {
            float v = p[k];
            if (v > best) { best = v; bj = k; }
        }
        sj[wv][lane] = bj;
    }
    asm volatile("" ::: "memory");

    // ---- P3: coalesced pure-store epilogue: 256 f4 = 4 KiB output span ----
    float4* __restrict__ og = (float4*)(out + rowbase + (wc << 10));
    const float4 xoarr[4] = {xo0, xo1, xo2, xo3};      // const-indexed -> regs
    #pragma unroll
    for (int r = 0; r < 4; ++r) {
        const int i  = lane + 64 * r;
        const int w  = i >> 2;                // window within chunk (broadcast x4)
        const int jm = sj[wv][w];
        const float4 v = xoarr[r];
        const int j0 = (i & 3) << 2;
        float4 o;
        o.x = (j0     == jm) ? v.x : 0.0f;
        o.y = (j0 + 1 == jm) ? v.y : 0.0f;
        o.z = (j0 + 2 == jm) ? v.z : 0.0f;
        o.w = (j0 + 3 == jm) ? v.w : 0.0f;
        __builtin_nontemporal_store(*(const nvec4*)&o, (nvec4*)&og[i]);
    }
}

extern "C" void kernel_launch(void* const* d_in, const int* in_sizes, int n_in,
                              void* d_out, int out_size, void* d_ws, size_t ws_size,
                              hipStream_t stream) {
    const float* x    = (const float*)d_in[0];
    const float* duty = (const float*)d_in[1];
    const float* bs   = (const float*)d_in[2];
    float* out = (float*)d_out;
    float* bf  = (float*)d_ws;   // 65536 floats = 256 KiB scratch

    hipLaunchKernelGGL(boost_table_kernel, dim3(NCOL / 256), dim3(256), 0, stream,
                       duty, bs, bf);
    hipLaunchKernelGGL(dkw_kernel, dim3(NWAVE / 4), dim3(256), 0, stream,
                       x, bf, out);
}